// Round 6
// baseline (707.715 us; speedup 1.0000x reference)
//
#include <hip/hip_runtime.h>
#include <hip/hip_bf16.h>
#include <hip/hip_fp16.h>

constexpr int BB = 4;
constexpr int CC = 512;
constexpr int HH = 4096;
constexpr int IC = 256;

typedef _Float16 f16x8v __attribute__((ext_vector_type(8)));
typedef __bf16   bf16x8v __attribute__((ext_vector_type(8)));
typedef float    f32x4v __attribute__((ext_vector_type(4)));

__device__ __forceinline__ void gll16(const void* g, void* l) {
  __builtin_amdgcn_global_load_lds(
      (const __attribute__((address_space(1))) unsigned int*)g,
      (__attribute__((address_space(3))) unsigned int*)l, 16, 0, 0);
}

__device__ __forceinline__ f32x4v mfma16(f16x8v a, f16x8v b, f32x4v c) {
  return __builtin_amdgcn_mfma_f32_16x16x32_f16(a, b, c, 0, 0, 0);
}
__device__ __forceinline__ f32x4v mfma16(bf16x8v a, bf16x8v b, f32x4v c) {
  return __builtin_amdgcn_mfma_f32_16x16x32_bf16(a, b, c, 0, 0, 0);
}

__device__ __forceinline__ unsigned short hbits(float f) {
  __half h = __float2half(f);
  unsigned short b; __builtin_memcpy(&b, &h, 2); return b;
}
__device__ __forceinline__ unsigned short bbits(float f) {
  __hip_bfloat16 h = __float2bfloat16(f);
  unsigned short b; __builtin_memcpy(&b, &h, 2); return b;
}

// ---------------------------------------------------------------------------
// 128x128-tile B^T GEMM (proven r3/r5 structure): C[m,n] = sum_k A[m,k]*B[n,k].
// 256 thr = 4 waves, 64x64 quadrants. C/D: col=lane&15, row=quad*4+reg.
// MODE 0: DUAL theta+phi (blockIdx.z>>2 selects B/bias/out). fp16, +bias[n].
// MODE 1: bf16, +bias[m]                         (g proj -> gB [IC,H])
// MODE 2: Z-ONLY scores: exp(v) column sums -> Z[b,n]; NO store of E.
// ---------------------------------------------------------------------------
template <int MODE>
__launch_bounds__(256)
__global__ void mgemm128(const void* __restrict__ Aall, const void* __restrict__ Ball,
                         const void* __restrict__ Ball2,
                         void* __restrict__ outP, void* __restrict__ out2P,
                         const float* __restrict__ bias, const float* __restrict__ bias2,
                         float* __restrict__ Z,
                         int M, int N, int K,
                         size_t sAb, size_t sBb, size_t sOb) {
  __shared__ __align__(16) unsigned short sA[128 * 32];
  __shared__ __align__(16) unsigned short sB[128 * 32];

  const int zz = blockIdx.z;
  int b, which;
  if constexpr (MODE == 0) { b = zz & (BB - 1); which = zz >> 2; }
  else { b = zz; which = 0; }

  const unsigned short* __restrict__ A = (const unsigned short*)Aall + (size_t)b * sAb;
  const unsigned short* __restrict__ Bm =
      (const unsigned short*)((MODE == 0 && which) ? Ball2 : Ball) + (size_t)b * sBb;
  const float* __restrict__ biasSel = (MODE == 0 && which) ? bias2 : bias;
  void* __restrict__ outSel = (MODE == 0 && which) ? out2P : outP;

  const int t = threadIdx.x;
  const int lane = t & 63;
  const int w = t >> 6;
  const int wm = (w >> 1) << 6;
  const int wn = (w & 1) << 6;
  const int mBase = blockIdx.y * 128;
  const int nBase = blockIdx.x * 128;

  const int fr = lane & 15;
  const int fo = (lane >> 4) << 3;

  f32x4v acc[4][4] = {};

  for (int k0 = 0; k0 < K; k0 += 32) {
#pragma unroll
    for (int p = 0; p < 2; ++p) {
      const int u = t + (p << 8);
      const int r = u >> 2;
      const int cs = (u & 3) << 3;
      gll16(A + (size_t)(mBase + r) * K + (k0 + cs), sA + u * 8);
      gll16(Bm + (size_t)(nBase + r) * K + (k0 + cs), sB + u * 8);
    }
    __syncthreads();
    f16x8v af[4], bf[4];
#pragma unroll
    for (int i = 0; i < 4; ++i)
      af[i] = *(const f16x8v*)(sA + ((wm + (i << 4) + fr) << 5) + fo);
#pragma unroll
    for (int j = 0; j < 4; ++j)
      bf[j] = *(const f16x8v*)(sB + ((wn + (j << 4) + fr) << 5) + fo);
#pragma unroll
    for (int i = 0; i < 4; ++i)
#pragma unroll
      for (int j = 0; j < 4; ++j)
        acc[i][j] = mfma16(af[i], bf[j], acc[i][j]);
    __syncthreads();
  }

  const int row0 = (lane >> 4) << 2;
  const int col = lane & 15;

  if constexpr (MODE == 2) {
    float csum[4] = {0.f, 0.f, 0.f, 0.f};
#pragma unroll
    for (int i = 0; i < 4; ++i)
#pragma unroll
      for (int j = 0; j < 4; ++j)
#pragma unroll
        for (int rg = 0; rg < 4; ++rg)
          csum[j] += __expf(acc[i][j][rg]);
#pragma unroll
    for (int j = 0; j < 4; ++j) {
      float s = csum[j];
      s += __shfl_xor(s, 16, 64);
      s += __shfl_xor(s, 32, 64);
      if (lane < 16) {
        const int n = nBase + wn + (j << 4) + col;
        atomicAdd(&Z[(size_t)b * N + n], s);
      }
    }
  } else {
#pragma unroll
    for (int i = 0; i < 4; ++i) {
      const int m0 = mBase + wm + (i << 4) + row0;
#pragma unroll
      for (int j = 0; j < 4; ++j) {
        const int n = nBase + wn + (j << 4) + col;
#pragma unroll
        for (int rg = 0; rg < 4; ++rg) {
          const int m = m0 + rg;
          const float v = acc[i][j][rg];
          if constexpr (MODE == 0) {
            ((__half*)outSel)[(size_t)b * sOb + (size_t)m * N + n] =
                __float2half(v + biasSel[n]);
          } else {
            ((__hip_bfloat16*)outP)[(size_t)b * sOb + (size_t)m * N + n] =
                __float2bfloat16(v + bias[m]);
          }
        }
      }
    }
  }
}

// ---------------------------------------------------------------------------
// Fused attention: ag[q,ic] = sum_k exp(theta_q . phi_k) * gs[ic,k], E never
// materialized. Per wave: 16 q. theta B-frags (8x bf16x8-equiv fp16) preloaded
// in registers. Key loop, 32 keys/iter:
//   S-MFMA x2 with PERMUTED phi rows: tile0 key = 8*quad + pos, tile1 +4
//   -> exp of the 8 C-regs packs IN-REGISTER into the exact K=32 PV B-frag
//   (lane: n=q=lane&15, k=8*quad+j). PV: 16 ic-tiles, A=gs[ic][k] b128 reads.
// No LDS, no barriers; phi/gs iter working set 32KB shared by all 4 waves ->
// L1-served. Split-K=2 -> fp16 partials P16[kc] (summed in finalgemm).
// grid (2, H/64, B) = 512 blocks.
// ---------------------------------------------------------------------------
__launch_bounds__(256)
__global__ void fusedattn(const __half* __restrict__ thetaAll,      // [B,H,IC]
                          const __half* __restrict__ phiAll,        // [B,H,IC]
                          const __hip_bfloat16* __restrict__ gAll,  // [B,IC,H] (pre /Z)
                          unsigned short* __restrict__ P16) {       // [2][B,H,IC] fp16
  const int b = blockIdx.z;
  const int kc = blockIdx.x;
  const int q16 = blockIdx.y * 64 + (threadIdx.x >> 6) * 16;
  const int lane = threadIdx.x & 63;
  const int l15 = lane & 15;
  const int l4 = lane >> 4;

  const unsigned short* __restrict__ th =
      (const unsigned short*)thetaAll + (size_t)b * HH * IC;
  const unsigned short* __restrict__ ph =
      (const unsigned short*)phiAll + (size_t)b * HH * IC;
  const unsigned short* __restrict__ gs =
      (const unsigned short*)gAll + (size_t)b * IC * HH;

  // theta B-fragments for this wave's 16 q, all 256 ic (8 chunks of 32)
  f16x8v thf[8];
#pragma unroll
  for (int c = 0; c < 8; ++c)
    thf[c] = *(const f16x8v*)(th + (size_t)(q16 + l15) * IC + c * 32 + l4 * 8);

  f32x4v acc[16] = {};  // PV acc: tile it -> col q=l15, row ic = it*16 + l4*4+reg

  // permuted phi row for S-tile0: m=l15 -> key offset 8*(m>>2) + (m&3)
  const int pr0 = ((l15 >> 2) << 3) + (l15 & 3);
  const int kstart = kc * 2048;

#pragma unroll 2
  for (int kk = 0; kk < 2048; kk += 32) {
    const int k0 = kstart + kk;
    const unsigned short* phB0 = ph + (size_t)(k0 + pr0) * IC + l4 * 8;
    const unsigned short* phB1 = phB0 + 4 * IC;  // tile1: +4 keys
    f32x4v s0 = {}, s1 = {};
#pragma unroll
    for (int c = 0; c < 8; ++c) {
      const f16x8v a0 = *(const f16x8v*)(phB0 + c * 32);
      const f16x8v a1 = *(const f16x8v*)(phB1 + c * 32);
      s0 = mfma16(a0, thf[c], s0);
      s1 = mfma16(a1, thf[c], s1);
    }
    // exp + pack: elem j = key 8*quad+j (tile0 j=0..3, tile1 j=4..7)
    bf16x8v pf;
#pragma unroll
    for (int r = 0; r < 4; ++r) {
      pf[r]     = (__bf16)__expf(s0[r]);
      pf[r + 4] = (__bf16)__expf(s1[r]);
    }
    // PV: A = gs[ic][k] (b128, k-contiguous), B = pf
#pragma unroll
    for (int it = 0; it < 16; ++it) {
      const bf16x8v ga =
          *(const bf16x8v*)(gs + (size_t)(it * 16 + l15) * HH + k0 + l4 * 8);
      acc[it] = mfma16(ga, pf, acc[it]);
    }
  }

  // store partials: P16[kc][b][q][ic], packed 4 consecutive ic per lane
  unsigned short* __restrict__ P =
      P16 + ((size_t)kc * BB + b) * HH * IC + (size_t)(q16 + l15) * IC;
#pragma unroll
  for (int it = 0; it < 16; ++it) {
    const int ic0 = it * 16 + (l4 << 2);
    ushort4 s = {hbits(acc[it][0]), hbits(acc[it][1]),
                 hbits(acc[it][2]), hbits(acc[it][3])};
    *(ushort4*)(P + ic0) = s;
  }
}

// ---------------------------------------------------------------------------
// Final GEMM: out[c,h] = w_mask[c,:] . (P0+P1)[h,:] + b_mask[c] + x[c,h].
// A = wm [C,IC] fp16; B = two fp16 partial chunks summed in-register
// (v_pk_add_f16) at fragment-read time. K = IC = 256.
// ---------------------------------------------------------------------------
__launch_bounds__(256)
__global__ void finalgemm(const __half* __restrict__ wm,
                          const unsigned short* __restrict__ P16,
                          const float* __restrict__ bias,
                          const float* __restrict__ xres,
                          float* __restrict__ out) {
  __shared__ __align__(16) unsigned short sA[128 * 32];
  __shared__ __align__(16) unsigned short sB0[128 * 32];
  __shared__ __align__(16) unsigned short sB1[128 * 32];

  const int b = blockIdx.z;
  const unsigned short* __restrict__ A = (const unsigned short*)wm;
  const unsigned short* __restrict__ B0 = P16 + (size_t)b * HH * IC;
  const unsigned short* __restrict__ B1 = B0 + (size_t)BB * HH * IC;

  const int t = threadIdx.x;
  const int lane = t & 63;
  const int w = t >> 6;
  const int wm_ = (w >> 1) << 6;
  const int wn = (w & 1) << 6;
  const int mBase = blockIdx.y * 128;   // c
  const int nBase = blockIdx.x * 128;   // h(q)

  const int fr = lane & 15;
  const int fo = (lane >> 4) << 3;

  f32x4v acc[4][4] = {};

  for (int k0 = 0; k0 < IC; k0 += 32) {
#pragma unroll
    for (int p = 0; p < 2; ++p) {
      const int u = t + (p << 8);
      const int r = u >> 2;
      const int cs = (u & 3) << 3;
      gll16(A + (size_t)(mBase + r) * IC + (k0 + cs), sA + u * 8);
      gll16(B0 + (size_t)(nBase + r) * IC + (k0 + cs), sB0 + u * 8);
      gll16(B1 + (size_t)(nBase + r) * IC + (k0 + cs), sB1 + u * 8);
    }
    __syncthreads();
    f16x8v af[4], bf[4];
#pragma unroll
    for (int i = 0; i < 4; ++i)
      af[i] = *(const f16x8v*)(sA + ((wm_ + (i << 4) + fr) << 5) + fo);
#pragma unroll
    for (int j = 0; j < 4; ++j) {
      const int o = ((wn + (j << 4) + fr) << 5) + fo;
      bf[j] = *(const f16x8v*)(sB0 + o) + *(const f16x8v*)(sB1 + o);
    }
#pragma unroll
    for (int i = 0; i < 4; ++i)
#pragma unroll
      for (int j = 0; j < 4; ++j)
        acc[i][j] = mfma16(af[i], bf[j], acc[i][j]);
    __syncthreads();
  }

  const int row0 = (lane >> 4) << 2;
  const int col = lane & 15;
#pragma unroll
  for (int i = 0; i < 4; ++i) {
    const int m0 = mBase + wm_ + (i << 4) + row0;
#pragma unroll
    for (int j = 0; j < 4; ++j) {
      const int n = nBase + wn + (j << 4) + col;
#pragma unroll
      for (int rg = 0; rg < 4; ++rg) {
        const int m = m0 + rg;
        const size_t o = (size_t)b * CC * HH + (size_t)m * HH + n;
        out[o] = acc[i][j][rg] + bias[m] + xres[o];
      }
    }
  }
}

// x [B,C,H] fp32 -> xT [B,H,C] fp16
__launch_bounds__(256)
__global__ void xpose(const float* __restrict__ x, __half* __restrict__ xT) {
  __shared__ float tile[64][65];
  const int b = blockIdx.z;
  const int h0 = blockIdx.x * 64;
  const int c0 = blockIdx.y * 64;
  const int lane = threadIdx.x & 63;
  const int r0 = threadIdx.x >> 6;
  const float* xb = x + (size_t)b * CC * HH;
#pragma unroll
  for (int rr = 0; rr < 16; ++rr) {
    const int c = r0 * 16 + rr;
    tile[c][lane] = xb[(size_t)(c0 + c) * HH + h0 + lane];
  }
  __syncthreads();
  __half* ob = xT + (size_t)b * HH * CC;
#pragma unroll
  for (int rr = 0; rr < 16; ++rr) {
    const int hl = r0 * 16 + rr;
    ob[(size_t)(h0 + hl) * CC + c0 + lane] = __float2half(tile[lane][hl]);
  }
}

// weight converts: all four weights -> fp16
__global__ void convw(const float* __restrict__ s0, const float* __restrict__ s1,
                      const float* __restrict__ s2, const float* __restrict__ s3,
                      __half* __restrict__ d0, __half* __restrict__ d1,
                      __half* __restrict__ d2, __half* __restrict__ d3) {
  const int which = blockIdx.y;
  const int i = (blockIdx.x * 256 + threadIdx.x) * 4;
  const float* s = which == 0 ? s0 : (which == 1 ? s1 : (which == 2 ? s2 : s3));
  __half* d = which == 0 ? d0 : (which == 1 ? d1 : (which == 2 ? d2 : d3));
  const float4 v = *(const float4*)(s + i);
  d[i] = __float2half(v.x); d[i + 1] = __float2half(v.y);
  d[i + 2] = __float2half(v.z); d[i + 3] = __float2half(v.w);
}

// gB [B,IC,H] bf16 /= Z[b,h]
__launch_bounds__(256)
__global__ void gscale(unsigned int* __restrict__ g, const float* __restrict__ Z) {
  const size_t tid = (size_t)blockIdx.x * 256 + threadIdx.x;
  const size_t e0 = tid * 8;
  const int b = (int)(e0 >> 20);
  const int h = (int)(e0 & (HH - 1));
  const float* Zp = Z + ((size_t)b << 12) + h;
  uint4 raw = ((const uint4*)g)[tid];
  unsigned short* u = (unsigned short*)&raw;
#pragma unroll
  for (int k = 0; k < 8; ++k) {
    const float f = __uint_as_float(((unsigned)u[k]) << 16) / Zp[k];
    u[k] = bbits(f);
  }
  ((uint4*)g)[tid] = raw;
}

// ---------------------------------------------------------------------------
extern "C" void kernel_launch(void* const* d_in, const int* in_sizes, int n_in,
                              void* d_out, int out_size, void* d_ws, size_t ws_size,
                              hipStream_t stream) {
  (void)in_sizes; (void)n_in; (void)out_size; (void)ws_size;

  const float* x       = (const float*)d_in[0];
  const float* w_phi   = (const float*)d_in[1];
  const float* b_phi   = (const float*)d_in[2];
  const float* w_theta = (const float*)d_in[3];
  const float* b_theta = (const float*)d_in[4];
  const float* w_g     = (const float*)d_in[5];
  const float* b_g     = (const float*)d_in[6];
  const float* w_mask  = (const float*)d_in[7];
  const float* b_mask  = (const float*)d_in[8];
  float* out = (float*)d_out;

  char* p = (char*)d_ws;
  __half* xT       = (__half*)p;                    p += (size_t)BB * HH * CC * 2;   // 16.8 MB
  __half* thetaH   = (__half*)p;                    p += (size_t)BB * HH * IC * 2;   // [h][ic]
  __half* phiH     = (__half*)p;                    p += (size_t)BB * HH * IC * 2;   // [h][ic]
  __hip_bfloat16* gB = (__hip_bfloat16*)p;          p += (size_t)BB * IC * HH * 2;   // [ic][h]
  __half* wthH = (__half*)p;                        p += (size_t)IC * CC * 2;
  __half* wphH = (__half*)p;                        p += (size_t)IC * CC * 2;
  __half* wgH  = (__half*)p;                        p += (size_t)IC * CC * 2;
  __half* wmH  = (__half*)p;                        p += (size_t)CC * IC * 2;
  float* Z = (float*)p;                             p += (size_t)BB * HH * 4;
  // fp16 ag partials (2 x 8.4 MB) alias xT (dead after projections)
  unsigned short* P16 = (unsigned short*)xT;

  const dim3 blk(256);

  convw<<<dim3(128, 4), blk, 0, stream>>>(w_phi, w_theta, w_g, w_mask, wphH, wthH, wgH, wmH);
  xpose<<<dim3(HH / 64, CC / 64, BB), blk, 0, stream>>>(x, xT);

  // theta/phi dual: A=xT [H,C], B=w_theta/w_phi [IC,C]; out [h][ic] fp16, +bias[ic]
  mgemm128<0><<<dim3(IC / 128, HH / 128, BB * 2), blk, 0, stream>>>(
      xT, wthH, wphH, thetaH, phiH, b_theta, b_phi, nullptr,
      HH, IC, CC, (size_t)HH * CC, 0, (size_t)HH * IC);

  // g: A=wg [IC,C], B=xT [H,C]; out gB[ic][h] bf16, +bias[ic=m]
  mgemm128<1><<<dim3(HH / 128, IC / 128, BB), blk, 0, stream>>>(
      wgH, xT, nullptr, gB, nullptr, b_g, nullptr, nullptr,
      IC, HH, CC, 0, (size_t)HH * CC, (size_t)IC * HH);

  // Z[b,k] = sum_q exp(theta_q . phi_k)  (no E store)
  hipMemsetAsync(Z, 0, (size_t)BB * HH * sizeof(float), stream);
  mgemm128<2><<<dim3(HH / 128, HH / 128, BB), blk, 0, stream>>>(
      thetaH, phiH, nullptr, nullptr, nullptr, nullptr, nullptr, Z,
      HH, HH, IC, (size_t)HH * IC, (size_t)HH * IC, 0);

  // g /= Z
  gscale<<<dim3((BB * IC * HH / 8) / 256), blk, 0, stream>>>((unsigned int*)gB, Z);

  // fused attention (E-free), split-K=2 fp16 partials
  fusedattn<<<dim3(2, HH / 64, BB), blk, 0, stream>>>(thetaH, phiH, gB, P16);

  // final: out[c,h] = wm . (P0+P1) + bias + x
  finalgemm<<<dim3(HH / 128, CC / 128, BB), blk, 0, stream>>>(
      wmH, P16, b_mask, x, out);
}

// Round 7
// 315.012 us; speedup vs baseline: 2.2466x; 2.2466x over previous
//
#include <hip/hip_runtime.h>
#include <hip/hip_bf16.h>
#include <hip/hip_fp16.h>
#include <type_traits>

constexpr int BB = 4;
constexpr int CC = 512;
constexpr int HH = 4096;
constexpr int IC = 256;

typedef _Float16 f16x8v __attribute__((ext_vector_type(8)));
typedef __bf16   bf16x8v __attribute__((ext_vector_type(8)));
typedef float    f32x4v __attribute__((ext_vector_type(4)));

__device__ __forceinline__ void gll16(const void* g, void* l) {
  __builtin_amdgcn_global_load_lds(
      (const __attribute__((address_space(1))) unsigned int*)g,
      (__attribute__((address_space(3))) unsigned int*)l, 16, 0, 0);
}

__device__ __forceinline__ f32x4v mfma16(f16x8v a, f16x8v b, f32x4v c) {
  return __builtin_amdgcn_mfma_f32_16x16x32_f16(a, b, c, 0, 0, 0);
}
__device__ __forceinline__ f32x4v mfma16(bf16x8v a, bf16x8v b, f32x4v c) {
  return __builtin_amdgcn_mfma_f32_16x16x32_bf16(a, b, c, 0, 0, 0);
}

__device__ __forceinline__ unsigned short hbits(float f) {
  __half h = __float2half(f);
  unsigned short b; __builtin_memcpy(&b, &h, 2); return b;
}
__device__ __forceinline__ unsigned short bbits(float f) {
  __hip_bfloat16 h = __float2bfloat16(f);
  unsigned short b; __builtin_memcpy(&b, &h, 2); return b;
}

// ---------------------------------------------------------------------------
// 128x128-tile B^T GEMM (r3/r5 proven): C[m,n] = sum_k A[m,k]*B[n,k].
// MODE 0: DUAL theta+phi (blockIdx.z>>2 selects B/bias/out). fp16, +bias[n].
// MODE 1: bf16, +bias[m]                        (g proj -> gB [IC,H])
// MODE 3: fp32, +bias[m] + xres                 (final + residual; bf16 in)
// ---------------------------------------------------------------------------
template <int MODE>
__launch_bounds__(256)
__global__ void mgemm128(const void* __restrict__ Aall, const void* __restrict__ Ball,
                         const void* __restrict__ Ball2,
                         void* __restrict__ outP, void* __restrict__ out2P,
                         const float* __restrict__ bias, const float* __restrict__ bias2,
                         const float* __restrict__ xres,
                         int M, int N, int K,
                         size_t sAb, size_t sBb, size_t sOb) {
  using ET = typename std::conditional<MODE == 3, bf16x8v, f16x8v>::type;

  __shared__ __align__(16) unsigned short sA[128 * 32];
  __shared__ __align__(16) unsigned short sB[128 * 32];

  const int zz = blockIdx.z;
  int b, which;
  if constexpr (MODE == 0) { b = zz & (BB - 1); which = zz >> 2; }
  else { b = zz; which = 0; }

  const unsigned short* __restrict__ A = (const unsigned short*)Aall + (size_t)b * sAb;
  const unsigned short* __restrict__ Bm =
      (const unsigned short*)((MODE == 0 && which) ? Ball2 : Ball) + (size_t)b * sBb;
  const float* __restrict__ biasSel = (MODE == 0 && which) ? bias2 : bias;
  void* __restrict__ outSel = (MODE == 0 && which) ? out2P : outP;

  const int t = threadIdx.x;
  const int lane = t & 63;
  const int w = t >> 6;
  const int wm = (w >> 1) << 6;
  const int wn = (w & 1) << 6;
  const int mBase = blockIdx.y * 128;
  const int nBase = blockIdx.x * 128;

  const int fr = lane & 15;
  const int fo = (lane >> 4) << 3;

  f32x4v acc[4][4] = {};

  for (int k0 = 0; k0 < K; k0 += 32) {
#pragma unroll
    for (int p = 0; p < 2; ++p) {
      const int u = t + (p << 8);
      const int r = u >> 2;
      const int cs = (u & 3) << 3;
      gll16(A + (size_t)(mBase + r) * K + (k0 + cs), sA + u * 8);
      gll16(Bm + (size_t)(nBase + r) * K + (k0 + cs), sB + u * 8);
    }
    __syncthreads();
    ET af[4], bf[4];
#pragma unroll
    for (int i = 0; i < 4; ++i)
      af[i] = *(const ET*)(sA + ((wm + (i << 4) + fr) << 5) + fo);
#pragma unroll
    for (int j = 0; j < 4; ++j)
      bf[j] = *(const ET*)(sB + ((wn + (j << 4) + fr) << 5) + fo);
#pragma unroll
    for (int i = 0; i < 4; ++i)
#pragma unroll
      for (int j = 0; j < 4; ++j)
        acc[i][j] = mfma16(af[i], bf[j], acc[i][j]);
    __syncthreads();
  }

  const int row0 = (lane >> 4) << 2;
  const int col = lane & 15;

#pragma unroll
  for (int i = 0; i < 4; ++i) {
    const int m0 = mBase + wm + (i << 4) + row0;
#pragma unroll
    for (int j = 0; j < 4; ++j) {
      const int n = nBase + wn + (j << 4) + col;
#pragma unroll
      for (int rg = 0; rg < 4; ++rg) {
        const int m = m0 + rg;
        const float v = acc[i][j][rg];
        if constexpr (MODE == 0) {
          ((__half*)outSel)[(size_t)b * sOb + (size_t)m * N + n] =
              __float2half(v + biasSel[n]);
        } else if constexpr (MODE == 1) {
          ((__hip_bfloat16*)outP)[(size_t)b * sOb + (size_t)m * N + n] =
              __float2bfloat16(v + bias[m]);
        } else {
          const size_t o = (size_t)b * sOb + (size_t)m * N + n;
          ((float*)outP)[o] = v + bias[m] + xres[o];
        }
      }
    }
  }
}

// ---------------------------------------------------------------------------
// Scores kernel -> blocked E. A = phi (m = keys, PERMUTED rows: the r6-verified
// trick), B = theta (n = q). For each (16q x 32k) sub-tile, the 8 exps per lane
// form EXACTLY the PV B-operand fragment (lane: q=lane&15, k=8*quad+j), stored
// as one contiguous 1KB record: E_blk[b][q16][k32][lane] (16B/lane packed).
// Also Z[b,key] += sum_q exp (fp32, atomics).
// ---------------------------------------------------------------------------
__launch_bounds__(256)
__global__ void scores_blk(const __half* __restrict__ thetaAll,
                           const __half* __restrict__ phiAll,
                           unsigned short* __restrict__ Eblk,
                           float* __restrict__ Z) {
  __shared__ __align__(16) unsigned short sA[128 * 32];  // phi (keys)
  __shared__ __align__(16) unsigned short sB[128 * 32];  // theta (q)

  const int b = blockIdx.z;
  const unsigned short* __restrict__ A =
      (const unsigned short*)phiAll + (size_t)b * HH * IC;
  const unsigned short* __restrict__ Bm =
      (const unsigned short*)thetaAll + (size_t)b * HH * IC;

  const int t = threadIdx.x;
  const int lane = t & 63;
  const int w = t >> 6;
  const int wk = (w >> 1) << 6;   // key quadrant
  const int wq = (w & 1) << 6;    // q quadrant
  const int kBase = blockIdx.y * 128;
  const int qBase = blockIdx.x * 128;

  const int fr = lane & 15;
  const int fo = (lane >> 4) << 3;
  const int pr0 = ((fr >> 2) << 3) + (fr & 3);  // permuted key row (r6-verified)

  f32x4v a0[2][4] = {};  // [key-chunk32][q-tile]
  f32x4v a1[2][4] = {};

  for (int k0 = 0; k0 < IC; k0 += 32) {
#pragma unroll
    for (int p = 0; p < 2; ++p) {
      const int u = t + (p << 8);
      const int r = u >> 2;
      const int cs = (u & 3) << 3;
      gll16(A + (size_t)(kBase + r) * IC + (k0 + cs), sA + u * 8);
      gll16(Bm + (size_t)(qBase + r) * IC + (k0 + cs), sB + u * 8);
    }
    __syncthreads();
    f16x8v af0[2], af1[2], bf[4];
#pragma unroll
    for (int ch = 0; ch < 2; ++ch) {
      af0[ch] = *(const f16x8v*)(sA + ((wk + (ch << 5) + pr0) << 5) + fo);
      af1[ch] = *(const f16x8v*)(sA + ((wk + (ch << 5) + pr0 + 4) << 5) + fo);
    }
#pragma unroll
    for (int j = 0; j < 4; ++j)
      bf[j] = *(const f16x8v*)(sB + ((wq + (j << 4) + fr) << 5) + fo);
#pragma unroll
    for (int ch = 0; ch < 2; ++ch)
#pragma unroll
      for (int j = 0; j < 4; ++j) {
        a0[ch][j] = mfma16(af0[ch], bf[j], a0[ch][j]);
        a1[ch][j] = mfma16(af1[ch], bf[j], a1[ch][j]);
      }
    __syncthreads();
  }

  // epilogue: exp -> packed fragment store + Z partial sums
  const int quad = lane >> 4;
  float csum[2][8];
#pragma unroll
  for (int ch = 0; ch < 2; ++ch)
#pragma unroll
    for (int s = 0; s < 8; ++s) csum[ch][s] = 0.f;

#pragma unroll
  for (int ch = 0; ch < 2; ++ch) {
    const int k32 = (kBase + wk + (ch << 5)) >> 5;
#pragma unroll
    for (int j = 0; j < 4; ++j) {
      float e[8];
#pragma unroll
      for (int r = 0; r < 4; ++r) {
        e[r]     = __expf(a0[ch][j][r]);
        e[r + 4] = __expf(a1[ch][j][r]);
      }
      bf16x8v pf;
#pragma unroll
      for (int s = 0; s < 8; ++s) {
        pf[s] = (__bf16)e[s];
        csum[ch][s] += e[s];
      }
      const int q16 = (qBase + wq + (j << 4)) >> 4;
      uint4 bits;
      __builtin_memcpy(&bits, &pf, 16);
      *(uint4*)(Eblk + ((((size_t)b * 256 + q16) * 128 + k32) << 9) + lane * 8) = bits;
    }
  }
#pragma unroll
  for (int ch = 0; ch < 2; ++ch) {
#pragma unroll
    for (int s = 0; s < 8; ++s) {
      float v = csum[ch][s];
      v += __shfl_xor(v, 1, 64);
      v += __shfl_xor(v, 2, 64);
      v += __shfl_xor(v, 4, 64);
      v += __shfl_xor(v, 8, 64);
      if (fr == 0) {
        const int key = kBase + wk + (ch << 5) + (quad << 3) + s;
        atomicAdd(&Z[(size_t)b * HH + key], v);
      }
    }
  }
}

// ---------------------------------------------------------------------------
// ag GEMM from blocked E. Block: 128 q x 256 ic (full IC -> E read ONCE),
// 4 waves: (w>>1)->q-group of 64, (w&1)->ic-group of 128. Split-K=4 (KC=1024).
// A = gs [IC,H] staged in LDS (16KB/iter, proven pattern). B = E_blk fragments
// loaded DIRECT from global: 16B/lane fully coalesced (1KB per fragment),
// register double-buffered across the barrier. fp16 partials, no atomics.
// ---------------------------------------------------------------------------
__launch_bounds__(256, 2)
__global__ void ag_blk(const __hip_bfloat16* __restrict__ Gall,
                       const unsigned short* __restrict__ Eblk,
                       unsigned short* __restrict__ P16) {
  constexpr int KC = 1024;
  __shared__ __align__(16) unsigned short sA[256 * 32];

  const int b = blockIdx.z;
  const int kc = blockIdx.x;
  const int qBase = blockIdx.y * 128;
  const int t = threadIdx.x;
  const int lane = t & 63;
  const int w = t >> 6;
  const int wq = (w >> 1) << 6;     // q-group (64)
  const int wic = (w & 1) << 7;     // ic-group (128)
  const int fr = lane & 15;
  const int fo = (lane >> 4) << 3;
  const int k0 = kc * KC;

  const unsigned short* __restrict__ G =
      (const unsigned short*)Gall + (size_t)b * IC * HH;
  // fragment base for this wave's 4 q16 tiles: record stride 512 ushorts
  const unsigned short* __restrict__ EB =
      Eblk + (((size_t)b * 256 + ((qBase + wq) >> 4)) << 16) + lane * 8;

  f32x4v acc[8][4] = {};
  bf16x8v bc[4], bn[4];

  {
    const int k32 = k0 >> 5;
#pragma unroll
    for (int j = 0; j < 4; ++j)
      bc[j] = *(const bf16x8v*)(EB + (((size_t)j * 128 + k32) << 9));
  }

  for (int kk = 0; kk < KC; kk += 32) {
#pragma unroll
    for (int p = 0; p < 4; ++p) {
      const int u = t + (p << 8);
      const int r = u >> 2;
      const int cs = (u & 3) << 3;
      gll16(G + (size_t)r * HH + (k0 + kk + cs), sA + u * 8);
    }
    __syncthreads();
    // prefetch next B fragments (overlaps the MFMA block below)
    {
      const int k32n = (k0 + kk + 32) >> 5;
#pragma unroll
      for (int j = 0; j < 4; ++j)
        bn[j] = *(const bf16x8v*)(EB + (((size_t)j * 128 + k32n) << 9));
    }
#pragma unroll
    for (int i = 0; i < 8; ++i) {
      const bf16x8v af =
          *(const bf16x8v*)(sA + ((wic + (i << 4) + fr) << 5) + fo);
#pragma unroll
      for (int j = 0; j < 4; ++j)
        acc[i][j] = mfma16(af, bc[j], acc[i][j]);
    }
    __syncthreads();
#pragma unroll
    for (int j = 0; j < 4; ++j) bc[j] = bn[j];
  }

  // store fp16 partials: C col = q = lane&15, row = ic = quad*4+reg (packed)
  unsigned short* __restrict__ P = P16 + ((size_t)kc * BB + b) * HH * IC;
  const int quad = lane >> 4;
#pragma unroll
  for (int i = 0; i < 8; ++i) {
    const int ic0 = wic + (i << 4) + (quad << 2);
#pragma unroll
    for (int j = 0; j < 4; ++j) {
      const int q = qBase + wq + (j << 4) + fr;
      ushort4 s = {hbits(acc[i][j][0]), hbits(acc[i][j][1]),
                   hbits(acc[i][j][2]), hbits(acc[i][j][3])};
      *(ushort4*)(P + (size_t)q * IC + ic0) = s;
    }
  }
}

// agB[b,q,ic] = bf16( sum_kc fp16 P16[kc][b][q][ic] ), 8 elems/thread (r5 proven)
__launch_bounds__(256)
__global__ void cvt_ag(const unsigned short* __restrict__ P16,
                       __hip_bfloat16* __restrict__ agB) {
  constexpr size_t CH = (size_t)BB * HH * IC;
  const size_t tIdx = (size_t)blockIdx.x * 256 + threadIdx.x;
  const f16x8v v0 = ((const f16x8v*)(P16))[tIdx];
  const f16x8v v1 = ((const f16x8v*)(P16 + CH))[tIdx];
  const f16x8v v2 = ((const f16x8v*)(P16 + 2 * CH))[tIdx];
  const f16x8v v3 = ((const f16x8v*)(P16 + 3 * CH))[tIdx];
  unsigned short o[8];
#pragma unroll
  for (int k = 0; k < 8; ++k) {
    const float s = (float)v0[k] + (float)v1[k] + (float)v2[k] + (float)v3[k];
    o[k] = bbits(s);
  }
  uint4 pack;
  __builtin_memcpy(&pack, o, 16);
  ((uint4*)agB)[tIdx] = pack;
}

// x [B,C,H] fp32 -> xT [B,H,C] fp16  (proven)
__launch_bounds__(256)
__global__ void xpose(const float* __restrict__ x, __half* __restrict__ xT) {
  __shared__ float tile[64][65];
  const int b = blockIdx.z;
  const int h0 = blockIdx.x * 64;
  const int c0 = blockIdx.y * 64;
  const int lane = threadIdx.x & 63;
  const int r0 = threadIdx.x >> 6;
  const float* xb = x + (size_t)b * CC * HH;
#pragma unroll
  for (int rr = 0; rr < 16; ++rr) {
    const int c = r0 * 16 + rr;
    tile[c][lane] = xb[(size_t)(c0 + c) * HH + h0 + lane];
  }
  __syncthreads();
  __half* ob = xT + (size_t)b * HH * CC;
#pragma unroll
  for (int rr = 0; rr < 16; ++rr) {
    const int hl = r0 * 16 + rr;
    ob[(size_t)(h0 + hl) * CC + c0 + lane] = __float2half(tile[lane][hl]);
  }
}

// weight converts: w_phi/w_theta/w_g -> fp16, w_mask -> bf16 (proven)
__global__ void convw(const float* __restrict__ s0, const float* __restrict__ s1,
                      const float* __restrict__ s2, const float* __restrict__ s3,
                      __half* __restrict__ d0, __half* __restrict__ d1,
                      __half* __restrict__ d2, __hip_bfloat16* __restrict__ d3) {
  const int which = blockIdx.y;
  const int i = (blockIdx.x * 256 + threadIdx.x) * 4;
  if (which < 3) {
    const float* s = which == 0 ? s0 : (which == 1 ? s1 : s2);
    __half* d = which == 0 ? d0 : (which == 1 ? d1 : d2);
    const float4 v = *(const float4*)(s + i);
    d[i] = __float2half(v.x); d[i + 1] = __float2half(v.y);
    d[i + 2] = __float2half(v.z); d[i + 3] = __float2half(v.w);
  } else {
    const float4 v = *(const float4*)(s3 + i);
    d3[i] = __float2bfloat16(v.x); d3[i + 1] = __float2bfloat16(v.y);
    d3[i + 2] = __float2bfloat16(v.z); d3[i + 3] = __float2bfloat16(v.w);
  }
}

// gB [B,IC,H] bf16 /= Z[b,h]  (proven)
__launch_bounds__(256)
__global__ void gscale(unsigned int* __restrict__ g, const float* __restrict__ Z) {
  const size_t tid = (size_t)blockIdx.x * 256 + threadIdx.x;
  const size_t e0 = tid * 8;
  const int b = (int)(e0 >> 20);
  const int h = (int)(e0 & (HH - 1));
  const float* Zp = Z + ((size_t)b << 12) + h;
  uint4 raw = ((const uint4*)g)[tid];
  unsigned short* u = (unsigned short*)&raw;
#pragma unroll
  for (int k = 0; k < 8; ++k) {
    const float f = __uint_as_float(((unsigned)u[k]) << 16) / Zp[k];
    u[k] = bbits(f);
  }
  ((uint4*)g)[tid] = raw;
}

// ---------------------------------------------------------------------------
extern "C" void kernel_launch(void* const* d_in, const int* in_sizes, int n_in,
                              void* d_out, int out_size, void* d_ws, size_t ws_size,
                              hipStream_t stream) {
  (void)in_sizes; (void)n_in; (void)out_size; (void)ws_size;

  const float* x       = (const float*)d_in[0];
  const float* w_phi   = (const float*)d_in[1];
  const float* b_phi   = (const float*)d_in[2];
  const float* w_theta = (const float*)d_in[3];
  const float* b_theta = (const float*)d_in[4];
  const float* w_g     = (const float*)d_in[5];
  const float* b_g     = (const float*)d_in[6];
  const float* w_mask  = (const float*)d_in[7];
  const float* b_mask  = (const float*)d_in[8];
  float* out = (float*)d_out;

  char* p = (char*)d_ws;
  unsigned short* Eblk = (unsigned short*)p;        p += (size_t)BB * HH * HH * 2;   // 134.2 MB
  __half* xT       = (__half*)p;                    p += (size_t)BB * HH * CC * 2;   // 16.8 MB
  __half* thetaH   = (__half*)p;                    p += (size_t)BB * HH * IC * 2;   // 8.4 MB
  __half* phiH     = (__half*)p;                    p += (size_t)BB * HH * IC * 2;   // 8.4 MB
  __hip_bfloat16* gB  = (__hip_bfloat16*)p;         p += (size_t)BB * IC * HH * 2;   // [ic][h]
  __hip_bfloat16* agB = (__hip_bfloat16*)p;         p += (size_t)BB * HH * IC * 2;   // [h][ic]
  __half* wthH = (__half*)p;                        p += (size_t)IC * CC * 2;
  __half* wphH = (__half*)p;                        p += (size_t)IC * CC * 2;
  __half* wgH  = (__half*)p;                        p += (size_t)IC * CC * 2;
  __hip_bfloat16* wmB = (__hip_bfloat16*)p;         p += (size_t)CC * IC * 2;
  float* Z = (float*)p;                             p += (size_t)BB * HH * 4;
  // fp16 split-K partials (4 x 8.4 MB = 33.6 MB) alias xT+theta+phi — all dead
  // by the time ag_blk runs (xT after projections, theta/phi after scores).
  unsigned short* P16 = (unsigned short*)xT;

  const dim3 blk(256);

  convw<<<dim3(128, 4), blk, 0, stream>>>(w_phi, w_theta, w_g, w_mask, wphH, wthH, wgH, wmB);
  xpose<<<dim3(HH / 64, CC / 64, BB), blk, 0, stream>>>(x, xT);

  // theta/phi dual: A=xT [H,C], B=w_theta/w_phi [IC,C]; out [h][ic] fp16, +bias[ic]
  mgemm128<0><<<dim3(IC / 128, HH / 128, BB * 2), blk, 0, stream>>>(
      xT, wthH, wphH, thetaH, phiH, b_theta, b_phi, nullptr,
      HH, IC, CC, (size_t)HH * CC, 0, (size_t)HH * IC);

  // g: A=wg [IC,C], B=xT [H,C]; out gB[ic][h] bf16, +bias[ic=m]
  mgemm128<1><<<dim3(HH / 128, IC / 128, BB), blk, 0, stream>>>(
      wgH, xT, nullptr, gB, nullptr, b_g, nullptr, nullptr,
      IC, HH, CC, 0, (size_t)HH * CC, (size_t)IC * HH);

  // scores -> blocked E fragments + Z
  hipMemsetAsync(Z, 0, (size_t)BB * HH * sizeof(float), stream);
  scores_blk<<<dim3(HH / 128, HH / 128, BB), blk, 0, stream>>>(thetaH, phiH, Eblk, Z);

  // g /= Z
  gscale<<<dim3((BB * IC * HH / 8) / 256), blk, 0, stream>>>((unsigned int*)gB, Z);

  // ag: split-K=4 from blocked E, fp16 partials, no atomics
  ag_blk<<<dim3(4, HH / 128, BB), blk, 0, stream>>>(gB, Eblk, P16);
  cvt_ag<<<dim3((BB * HH * IC / 8) / 256), blk, 0, stream>>>(P16, agB);

  // final: A=wm [C,IC] bf16, B=agB [H,IC] bf16; out[c][h] fp32 + bias[c] + x
  mgemm128<3><<<dim3(HH / 128, CC / 128, BB), blk, 0, stream>>>(
      wmB, agB, nullptr, out, nullptr, b_mask, nullptr, x,
      CC, HH, IC, 0, (size_t)HH * IC, (size_t)CC * HH);
}